// Round 1
// 241.727 us; speedup vs baseline: 1.0338x; 1.0338x over previous
//
#include <hip/hip_runtime.h>
#include <math.h>

#define NUM_GT   128
#define NUM_PROP 512
#define IMG_H    520
#define IMG_W    704
#define MS       28
#define LOGITS_N (NUM_PROP * 2 * MS * MS)   // 802816
#define SQ_BLOCKS 128
#define TOTAL_BLOCKS (NUM_PROP + SQ_BLOCKS) // 640

// Self-contained accumulators: no d_ws usage at all.
// Zero-initialized at module load; the LAST block of each launch resets them,
// so every launch (and every graph replay) starts from zero.
__device__ float    g_bce  = 0.0f;
__device__ float    g_npos = 0.0f;
__device__ float    g_sq   = 0.0f;
__device__ unsigned g_done = 0u;

__global__ __launch_bounds__(256) void fused_kernel(
        const float* __restrict__ proposals,
        const float* __restrict__ gt_boxes,
        const float* __restrict__ gt_masks,
        const float* __restrict__ mask_logits,
        float* __restrict__ out)
{
    const int b = blockIdx.x;
    const int t = threadIdx.x;

    if (b < NUM_PROP) {
        // ---------- per-proposal block: match + crop-resize + BCE ----------
        const int p = b;
        __shared__ float s_iou[NUM_GT];
        __shared__ int   s_idx[NUM_GT];
        __shared__ int   s_x0[MS], s_x1[MS], s_y0[MS], s_y1[MS];
        __shared__ float s_wx[MS], s_wy[MS];
        __shared__ float red[4];

        // proposal box (broadcast load — same 4 floats for all lanes)
        const float ax1 = proposals[p * 4 + 0];
        const float ay1 = proposals[p * 4 + 1];
        const float ax2 = proposals[p * 4 + 2];
        const float ay2 = proposals[p * 4 + 3];
        const float area_a = (ax2 - ax1) * (ay2 - ay1);

        // one IoU per lane (128 GTs, lanes 0..127)
        if (t < NUM_GT) {
            float bx1 = gt_boxes[t * 4 + 0];
            float by1 = gt_boxes[t * 4 + 1];
            float bx2 = gt_boxes[t * 4 + 2];
            float by2 = gt_boxes[t * 4 + 3];
            float area_b = (bx2 - bx1) * (by2 - by1);
            float w = fmaxf(fminf(ax2, bx2) - fmaxf(ax1, bx1), 0.0f);
            float h = fmaxf(fminf(ay2, by2) - fmaxf(ay1, by1), 0.0f);
            float inter = w * h;
            s_iou[t] = inter / (area_a + area_b - inter);
            s_idx[t] = t;
        }
        __syncthreads();

        // argmax tree-reduce; ties -> smaller index (matches jnp.argmax first-occurrence)
        for (int s = NUM_GT / 2; s > 0; s >>= 1) {
            if (t < s) {
                float a = s_iou[t], c = s_iou[t + s];
                int   ia = s_idx[t], ic = s_idx[t + s];
                if (c > a || (c == a && ic < ia)) { s_iou[t] = c; s_idx[t] = ic; }
            }
            __syncthreads();
        }
        const float best = s_iou[0];
        const int   g    = s_idx[0];
        const float ps   = (best > 0.5f) ? 1.0f : 0.0f;

        if (t == 0) atomicAdd(&g_npos, ps);

        if (ps != 0.0f) {   // pos==0 blocks contribute exactly 0 to bce_sum — skip
            // matched gt box (broadcast)
            const float b0 = gt_boxes[g * 4 + 0];
            const float b1 = gt_boxes[g * 4 + 1];
            const float b2 = gt_boxes[g * 4 + 2];
            const float b3 = gt_boxes[g * 4 + 3];

            // int cast truncates toward zero, matching astype(int32)
            int x1 = min(max((int)b0, 0), IMG_W - 1);
            int y1 = min(max((int)b1, 0), IMG_H - 1);
            int x2 = max(x1 + 1, min((int)b2, IMG_W));
            int y2 = max(y1 + 1, min((int)b3, IMG_H));
            int cwi = x2 - x1;
            int chi = y2 - y1;
            float cw = (float)cwi;
            float ch = (float)chi;

            if (t < MS) {
                float j = (float)t + 0.5f;
                float sx = fminf(fmaxf(j * cw / 28.0f - 0.5f, 0.0f), cw - 1.0f);
                float x0f = floorf(sx);
                int x0i = (int)x0f;
                s_wx[t] = sx - x0f;
                s_x0[t] = x0i + x1;
                s_x1[t] = min(x0i + 1, cwi - 1) + x1;

                float sy = fminf(fmaxf(j * ch / 28.0f - 0.5f, 0.0f), ch - 1.0f);
                float y0f = floorf(sy);
                int y0i = (int)y0f;
                s_wy[t] = sy - y0f;
                s_y0[t] = y0i + y1;
                s_y1[t] = min(y0i + 1, chi - 1) + y1;
            }
            __syncthreads();

            const float* m  = gt_masks + (size_t)g * IMG_H * IMG_W;
            const float* lg = mask_logits + ((size_t)p * 2 + 1) * (MS * MS);

            float acc = 0.0f;
            for (int idx = t; idx < MS * MS; idx += 256) {
                int i = idx / MS;
                int j = idx - i * MS;
                float wx = s_wx[j], wy = s_wy[i];
                const float* r0 = m + (size_t)s_y0[i] * IMG_W;
                const float* r1 = m + (size_t)s_y1[i] * IMG_W;
                int cx0 = s_x0[j], cx1 = s_x1[j];
                float v00 = r0[cx0], v01 = r0[cx1];
                float v10 = r1[cx0], v11 = r1[cx1];
                float top = (1.0f - wx) * v00 + wx * v01;
                float bot = (1.0f - wx) * v10 + wx * v11;
                float tv  = (1.0f - wy) * top + wy * bot;
                float l = lg[idx];
                acc += fmaxf(l, 0.0f) - l * tv + log1pf(expf(-fabsf(l)));
            }

            // block reduce (4 waves of 64)
            float v = acc;
            #pragma unroll
            for (int o = 32; o > 0; o >>= 1) v += __shfl_down(v, o, 64);
            int lane = t & 63, wid = t >> 6;
            if (lane == 0) red[wid] = v;
            __syncthreads();
            if (t == 0) {
                float s = red[0] + red[1] + red[2] + red[3];
                atomicAdd(&g_bce, s * ps);   // ps == 1.0f here
            }
        }
    } else {
        // ---------- sq blocks: sum(mask_logits^2) ----------
        const int sb = b - NUM_PROP;
        const int nvec = LOGITS_N / 4;  // 200704
        const float4* src = (const float4*)mask_logits;
        float acc = 0.0f;
        for (int i = sb * 256 + t; i < nvec; i += SQ_BLOCKS * 256) {
            float4 x = src[i];
            acc += x.x * x.x + x.y * x.y + x.z * x.z + x.w * x.w;
        }
        float v = acc;
        #pragma unroll
        for (int o = 32; o > 0; o >>= 1) v += __shfl_down(v, o, 64);
        __shared__ float redq[4];
        int lane = t & 63, wid = t >> 6;
        if (lane == 0) redq[wid] = v;
        __syncthreads();
        if (t == 0) {
            atomicAdd(&g_sq, redq[0] + redq[1] + redq[2] + redq[3]);
        }
    }

    // ---------- last-block finalize + self-reset ----------
    // All global accumulator writes above were performed by thread 0 of each
    // block; program order + threadfence orders them before the done-count.
    if (t == 0) {
        __threadfence();
        unsigned prev = atomicAdd(&g_done, 1u);
        if (prev == TOTAL_BLOCKS - 1) {
            // read via RMW so we observe the fully-merged device-coherent values
            float bce  = atomicAdd(&g_bce,  0.0f);
            float npos = atomicAdd(&g_npos, 0.0f);
            float sq   = atomicAdd(&g_sq,   0.0f);
            float loss_pos = bce / (fmaxf(npos, 1.0f) * (float)(MS * MS));
            float loss_neg = (sq / (float)LOGITS_N) * 0.01f;
            out[0] = (npos > 0.0f) ? loss_pos : loss_neg;
            // reset for the next launch / graph replay
            atomicExch(&g_bce,  0.0f);
            atomicExch(&g_npos, 0.0f);
            atomicExch(&g_sq,   0.0f);
            __threadfence();
            atomicExch(&g_done, 0u);
        }
    }
}

extern "C" void kernel_launch(void* const* d_in, const int* in_sizes, int n_in,
                              void* d_out, int out_size, void* d_ws, size_t ws_size,
                              hipStream_t stream) {
    (void)in_sizes; (void)n_in; (void)d_ws; (void)ws_size; (void)out_size;
    const float* proposals   = (const float*)d_in[0];
    const float* gt_boxes    = (const float*)d_in[1];
    const float* gt_masks    = (const float*)d_in[2];
    const float* mask_logits = (const float*)d_in[3];
    float* out = (float*)d_out;

    fused_kernel<<<TOTAL_BLOCKS, 256, 0, stream>>>(proposals, gt_boxes, gt_masks,
                                                   mask_logits, out);
}